// Round 11
// baseline (39.044 us; speedup 1.0000x reference)
//
#include <hip/hip_runtime.h>

namespace {

constexpr int CH  = 8;     // hidden/out channels
constexpr int CIN = 8;     // feature channels
constexpr int HH  = 100;
constexpr int WW  = 136;
constexpr int HW  = HH * WW;   // 13600
constexpr int NP  = 232;       // params per instance
constexpr int VP  = 4;         // pixels per thread (float4), processed as 2x f32x2
constexpr int NG  = 2;         // f32x2 groups
constexpr int BLK = 256;

typedef float f32x4 __attribute__((ext_vector_type(4)));
typedef float f32x2 __attribute__((ext_vector_type(2)));

// param layout per instance (flat 232):
//  w1[o][i] = p[o*10 + i]   o<8, i<10  (i=0: rel_x, i=1: rel_y, i=2+c: feat c)
//  w2[o][i] = p[80  + o*8 + i]
//  w3[o][i] = p[144 + o*8 + i]
//  b1[o]=p[208+o]  b2[o]=p[216+o]  b3[o]=p[224+o]

__global__ __launch_bounds__(BLK)
void dmh_kernel(const float* __restrict__ feats,     // (N_IMG, CIN, HW)
                const float* __restrict__ params,    // (n_inst, NP)
                const float* __restrict__ ilocs,     // (n_inst, 2)
                const int*   __restrict__ im_inds,   // (n_inst)
                const int*   __restrict__ lvls,      // (n_inst)
                const int*   __restrict__ stride_p,  // (1)
                float*       __restrict__ out)       // (n_inst, CH, HW)
{
    const int n   = blockIdx.y;
    const int tid = threadIdx.x;

    __shared__ float sp[NP];
    if (tid < NP) sp[tid] = params[(size_t)n * NP + tid];
    __syncthreads();

    const int p0 = (blockIdx.x * BLK + tid) * VP;
    if (p0 >= HW) return;

    // per-instance uniforms
    const int   im  = im_inds[n];
    const int   lvl = lvls[n];
    const float soi_tab[5] = {64.f, 128.f, 256.f, 512.f, 1024.f};
    const float inv_soi = 1.0f / soi_tab[lvl];
    const float ix = ilocs[2 * n + 0];
    const float iy = ilocs[2 * n + 1];

    // stride scalar: tolerate int32 or float32 encoding
    const int   s_i = stride_p[0];
    const float fs  = (s_i >= 1 && s_i <= 65536) ? (float)s_i : __int_as_float(s_i);
    const float fh  = floorf(fs * 0.5f);   // stride // 2

    // load 8 feature channels x 4 pixels; keep as 2x f32x2 per channel
    f32x2 f[CIN][NG];
    const float* fbase = feats + (size_t)im * CIN * HW + p0;
    #pragma unroll
    for (int c = 0; c < CIN; ++c) {
        const f32x4 v = *reinterpret_cast<const f32x4*>(fbase + c * HW);
        f[c][0] = __builtin_shufflevector(v, v, 0, 1);
        f[c][1] = __builtin_shufflevector(v, v, 2, 3);
    }

    // relative coordinates as f32x2 pairs
    f32x2 relx[NG], rely[NG];
    #pragma unroll
    for (int g = 0; g < NG; ++g) {
        #pragma unroll
        for (int k = 0; k < 2; ++k) {
            const int pp = p0 + g * 2 + k;
            const int y  = pp / WW;
            const int x  = pp - y * WW;
            relx[g][k] = (ix - ((float)x * fs + fh)) * inv_soi;
            rely[g][k] = (iy - ((float)y * fs + fh)) * inv_soi;
        }
    }

    const f32x2 zero = {0.f, 0.f};

    // layer 1: 10 -> 8, ReLU   (packed f32x2 math -> v_pk_fma_f32)
    f32x2 h1[CH][NG];
    #pragma unroll
    for (int o = 0; o < CH; ++o) {
        const float wx = sp[o * 10 + 0];
        const float wy = sp[o * 10 + 1];
        const float b  = sp[208 + o];
        #pragma unroll
        for (int g = 0; g < NG; ++g) {
            f32x2 a = {b, b};
            a = relx[g] * wx + a;
            a = rely[g] * wy + a;
            #pragma unroll
            for (int c = 0; c < CIN; ++c)
                a = f[c][g] * sp[o * 10 + 2 + c] + a;
            h1[o][g] = __builtin_elementwise_max(a, zero);
        }
    }

    // layer 2: 8 -> 8, ReLU
    f32x2 h2[CH][NG];
    #pragma unroll
    for (int o = 0; o < CH; ++o) {
        const float b = sp[216 + o];
        #pragma unroll
        for (int g = 0; g < NG; ++g) {
            f32x2 a = {b, b};
            #pragma unroll
            for (int i = 0; i < CH; ++i)
                a = h1[i][g] * sp[80 + o * 8 + i] + a;
            h2[o][g] = __builtin_elementwise_max(a, zero);
        }
    }

    // layer 3: 8 -> 8, ReLU + coalesced float4 store
    float* ob = out + (size_t)n * CH * HW + p0;
    #pragma unroll
    for (int o = 0; o < CH; ++o) {
        const float b = sp[224 + o];
        f32x2 r[NG];
        #pragma unroll
        for (int g = 0; g < NG; ++g) {
            f32x2 a = {b, b};
            #pragma unroll
            for (int i = 0; i < CH; ++i)
                a = h2[i][g] * sp[144 + o * 8 + i] + a;
            r[g] = __builtin_elementwise_max(a, zero);
        }
        f32x4 v;
        v.x = r[0].x; v.y = r[0].y; v.z = r[1].x; v.w = r[1].y;
        *reinterpret_cast<f32x4*>(ob + o * HW) = v;
    }
}

} // namespace

extern "C" void kernel_launch(void* const* d_in, const int* in_sizes, int n_in,
                              void* d_out, int out_size, void* d_ws, size_t ws_size,
                              hipStream_t stream) {
    const float* feats  = (const float*)d_in[0];
    const float* params = (const float*)d_in[1];
    const float* ilocs  = (const float*)d_in[2];
    const int*   im     = (const int*)d_in[3];
    const int*   lv     = (const int*)d_in[4];
    const int*   st     = (const int*)d_in[5];
    float*       out    = (float*)d_out;

    const int n_inst = in_sizes[1] / NP;   // 400
    dim3 grid((HW + BLK * VP - 1) / (BLK * VP), n_inst);
    dmh_kernel<<<grid, BLK, 0, stream>>>(feats, params, ilocs, im, lv, st, out);
}